// Round 4
// baseline (480.287 us; speedup 1.0000x reference)
//
#include <hip/hip_runtime.h>
#include <math.h>

#define LL 2048
#define BB 128
#define HH 300
#define HV4 75   // HH / 4

// Kernel 1: v_t[b][h] = sum_k W[k][h] * hidden[k][b]   (= (W^T @ hidden)^T)
__global__ void __launch_bounds__(256) compute_v(const float* __restrict__ W,
                                                 const float* __restrict__ hidden,
                                                 float* __restrict__ v_t) {
    int b   = blockIdx.x;
    int tid = threadIdx.x;
    __shared__ float hcol[HH];
    for (int k = tid; k < HH; k += 256) hcol[k] = hidden[k * BB + b];
    __syncthreads();
    for (int h = tid; h < HH; h += 256) {
        float s = 0.f;
#pragma unroll 4
        for (int k = 0; k < HH; ++k)
            s = fmaf(W[k * HH + h], hcol[k], s);
        v_t[b * HH + h] = s;
    }
}

// Kernel 2 (the 315 MB stream) — EXACT R1 structure (best measured):
// one wave per row in memory order (row = l*BB + b), each block reads
// 4800 B contiguous, consecutive blocks contiguous; energies written [L][B]
// so each block's 4 lane-0 writes are 16 B contiguous.
// Bias omitted: adds a per-b constant along the softmax axis -> no-op.
__global__ void __launch_bounds__(256) compute_energies(
        const float4* __restrict__ qv4,
        const float4* __restrict__ v4,
        float* __restrict__ energies) {
    int row  = blockIdx.x * 4 + (threadIdx.x >> 6);  // row = l*BB + b
    int lane = threadIdx.x & 63;
    int b    = row & (BB - 1);

    const float4* q = qv4 + (size_t)row * HV4;
    const float4* v = v4  + (size_t)b * HV4;

    float4 a0 = q[lane];
    float4 b0 = v[lane];
    float s = a0.x * b0.x + a0.y * b0.y + a0.z * b0.z + a0.w * b0.w;
    if (lane < HV4 - 64) {        // lanes 0..10 cover elements 64..74
        float4 a1 = q[64 + lane];
        float4 b1 = v[64 + lane];
        s += a1.x * b1.x + a1.y * b1.y + a1.z * b1.z + a1.w * b1.w;
    }
#pragma unroll
    for (int off = 32; off > 0; off >>= 1)
        s += __shfl_down(s, off, 64);
    if (lane == 0)
        energies[row] = s;                           // [L][B], 16 B/block contiguous
}

// Kernel 3: softmax over l. One block per 4-wide b-group (g = blockIdx, 32
// blocks). Reads energies[L][B] as float4 across b (one 16 B load covers 4 b's
// at one l) -> 4x fewer L2 txns than scalar column reads, zero wasted bytes.
// Componentwise block max/sum reduction; writes out[b][l] coalesced over l.
__global__ void __launch_bounds__(256) softmax_g4(
        const float4* __restrict__ e4,   // energies as [L][B/4] float4
        float* __restrict__ out) {
    int g    = blockIdx.x;               // b-group: b = 4g..4g+3
    int tid  = threadIdx.x;
    int lane = tid & 63;
    int wave = tid >> 6;

    __shared__ float4 redm[4];
    __shared__ float4 reds[4];

    float4 v[8];
    float4 m = make_float4(-INFINITY, -INFINITY, -INFINITY, -INFINITY);
#pragma unroll
    for (int i = 0; i < 8; ++i) {
        int l = tid + i * 256;
        v[i] = e4[(size_t)l * (BB / 4) + g];
        m.x = fmaxf(m.x, v[i].x); m.y = fmaxf(m.y, v[i].y);
        m.z = fmaxf(m.z, v[i].z); m.w = fmaxf(m.w, v[i].w);
    }
#pragma unroll
    for (int off = 32; off > 0; off >>= 1) {
        m.x = fmaxf(m.x, __shfl_down(m.x, off, 64));
        m.y = fmaxf(m.y, __shfl_down(m.y, off, 64));
        m.z = fmaxf(m.z, __shfl_down(m.z, off, 64));
        m.w = fmaxf(m.w, __shfl_down(m.w, off, 64));
    }
    if (lane == 0) redm[wave] = m;
    __syncthreads();
    {
        float4 a = redm[0], b2 = redm[1], c = redm[2], d = redm[3];
        m.x = fmaxf(fmaxf(a.x, b2.x), fmaxf(c.x, d.x));
        m.y = fmaxf(fmaxf(a.y, b2.y), fmaxf(c.y, d.y));
        m.z = fmaxf(fmaxf(a.z, b2.z), fmaxf(c.z, d.z));
        m.w = fmaxf(fmaxf(a.w, b2.w), fmaxf(c.w, d.w));
    }

    float4 s = make_float4(0.f, 0.f, 0.f, 0.f);
#pragma unroll
    for (int i = 0; i < 8; ++i) {
        v[i].x = __expf(v[i].x - m.x); s.x += v[i].x;
        v[i].y = __expf(v[i].y - m.y); s.y += v[i].y;
        v[i].z = __expf(v[i].z - m.z); s.z += v[i].z;
        v[i].w = __expf(v[i].w - m.w); s.w += v[i].w;
    }
#pragma unroll
    for (int off = 32; off > 0; off >>= 1) {
        s.x += __shfl_down(s.x, off, 64);
        s.y += __shfl_down(s.y, off, 64);
        s.z += __shfl_down(s.z, off, 64);
        s.w += __shfl_down(s.w, off, 64);
    }
    if (lane == 0) reds[wave] = s;
    __syncthreads();
    {
        float4 a = reds[0], b2 = reds[1], c = reds[2], d = reds[3];
        s.x = (a.x + b2.x) + (c.x + d.x);
        s.y = (a.y + b2.y) + (c.y + d.y);
        s.z = (a.z + b2.z) + (c.z + d.z);
        s.w = (a.w + b2.w) + (c.w + d.w);
    }
    float4 inv = make_float4(1.f / s.x, 1.f / s.y, 1.f / s.z, 1.f / s.w);

    float* o0 = out + (size_t)(4 * g + 0) * LL;
    float* o1 = out + (size_t)(4 * g + 1) * LL;
    float* o2 = out + (size_t)(4 * g + 2) * LL;
    float* o3 = out + (size_t)(4 * g + 3) * LL;
#pragma unroll
    for (int i = 0; i < 8; ++i) {
        int l = tid + i * 256;
        o0[l] = v[i].x * inv.x;          // coalesced: consecutive tid -> consecutive l
        o1[l] = v[i].y * inv.y;
        o2[l] = v[i].z * inv.z;
        o3[l] = v[i].w * inv.w;
    }
}

extern "C" void kernel_launch(void* const* d_in, const int* in_sizes, int n_in,
                              void* d_out, int out_size, void* d_ws, size_t ws_size,
                              hipStream_t stream) {
    const float* hidden = (const float*)d_in[0];   // [H, B]
    const float* qv     = (const float*)d_in[1];   // [L, B, H]
    const float* W      = (const float*)d_in[2];   // [H, H]
    // d_in[3] = bias[H]: softmax-shift-invariant, intentionally unused.
    float* out = (float*)d_out;                    // [B, L]

    float* v_t      = (float*)d_ws;                // BB*HH floats (153600 B, 16B-aligned)
    float* energies = v_t + BB * HH;               // LL*BB floats = 1 MB, [L][B]

    compute_v<<<BB, 256, 0, stream>>>(W, hidden, v_t);
    compute_energies<<<(LL * BB) / 4, 256, 0, stream>>>(
        (const float4*)qv, (const float4*)v_t, energies);
    softmax_g4<<<BB / 4, 256, 0, stream>>>((const float4*)energies, out);
}

// Round 5
// 450.041 us; speedup vs baseline: 1.0672x; 1.0672x over previous
//
#include <hip/hip_runtime.h>
#include <math.h>

#define LL 2048
#define BB 128
#define HH 300
#define HV4 75   // HH / 4

// ===== EXACT R1 kernel set — best measured (450 µs vs 476-491 for all
// later variants; all deltas since were within harness fill noise). =====

// Kernel 1: v_t[b][h] = sum_k W[k][h] * hidden[k][b]   (= (W^T @ hidden)^T)
// Tiny: 38400 outputs x 300 MACs. W reads coalesced (consecutive h per
// thread), hidden reads broadcast. All L2-resident after first touch.
__global__ void __launch_bounds__(256) compute_v(const float* __restrict__ W,
                                                 const float* __restrict__ hidden,
                                                 float* __restrict__ v_t) {
    int t = blockIdx.x * blockDim.x + threadIdx.x;
    if (t >= BB * HH) return;
    int b = t / HH;
    int h = t - b * HH;
    float s = 0.f;
#pragma unroll 4
    for (int k = 0; k < HH; ++k)
        s = fmaf(W[k * HH + h], hidden[k * BB + b], s);
    v_t[b * HH + h] = s;
}

// Kernel 2 (the 315 MB stream — the roofline term): one wave per (l,b) row,
// rows in memory order so the grid streams qv linearly (4800 B contiguous per
// block, consecutive blocks contiguous). energies written [L][B]: each
// block's 4 lane-0 writes are 16 B contiguous.
// Bias omitted: adds a per-b constant along the softmax axis -> no-op under
// softmax shift invariance.
__global__ void __launch_bounds__(256) compute_energies(
        const float4* __restrict__ qv4,
        const float4* __restrict__ v4,
        float* __restrict__ energies) {
    int wave = threadIdx.x >> 6;
    int lane = threadIdx.x & 63;
    int row  = blockIdx.x * 4 + wave;          // row = l*BB + b
    int b    = row & (BB - 1);

    const float4* q = qv4 + (size_t)row * HV4;
    const float4* v = v4  + (size_t)b   * HV4;

    float4 a0 = q[lane];
    float4 b0 = v[lane];
    float s = a0.x * b0.x + a0.y * b0.y + a0.z * b0.z + a0.w * b0.w;
    if (lane < HV4 - 64) {                     // lanes 0..10 cover elements 64..74
        float4 a1 = q[64 + lane];
        float4 b1 = v[64 + lane];
        s += a1.x * b1.x + a1.y * b1.y + a1.z * b1.z + a1.w * b1.w;
    }
#pragma unroll
    for (int off = 32; off > 0; off >>= 1)
        s += __shfl_down(s, off, 64);
    if (lane == 0)
        energies[row] = s;
}

// Kernel 3: softmax over l for each b. One block per b; energies [L][B] so
// element l is at energies[l*BB + b] (stride-512B column reads — 1 MB,
// L2-resident, measured-neutral vs all coalesced variants).
__global__ void __launch_bounds__(256) softmax_rows(
        const float* __restrict__ energies,
        float* __restrict__ out) {
    int b    = blockIdx.x;
    int tid  = threadIdx.x;
    int lane = tid & 63;
    int wave = tid >> 6;

    __shared__ float redm[4];
    __shared__ float reds[4];

    float vals[8];
    float m = -INFINITY;
#pragma unroll
    for (int i = 0; i < 8; ++i) {
        int l = tid + i * 256;
        vals[i] = energies[l * BB + b];
        m = fmaxf(m, vals[i]);
    }
#pragma unroll
    for (int off = 32; off > 0; off >>= 1)
        m = fmaxf(m, __shfl_down(m, off, 64));
    if (lane == 0) redm[wave] = m;
    __syncthreads();
    m = fmaxf(fmaxf(redm[0], redm[1]), fmaxf(redm[2], redm[3]));

    float s = 0.f;
#pragma unroll
    for (int i = 0; i < 8; ++i) {
        vals[i] = __expf(vals[i] - m);
        s += vals[i];
    }
#pragma unroll
    for (int off = 32; off > 0; off >>= 1)
        s += __shfl_down(s, off, 64);
    if (lane == 0) reds[wave] = s;
    __syncthreads();
    s = reds[0] + reds[1] + reds[2] + reds[3];
    float inv = 1.f / s;

#pragma unroll
    for (int i = 0; i < 8; ++i)
        out[b * LL + tid + i * 256] = vals[i] * inv;
}

extern "C" void kernel_launch(void* const* d_in, const int* in_sizes, int n_in,
                              void* d_out, int out_size, void* d_ws, size_t ws_size,
                              hipStream_t stream) {
    const float* hidden = (const float*)d_in[0];   // [H, B]
    const float* qv     = (const float*)d_in[1];   // [L, B, H]
    const float* W      = (const float*)d_in[2];   // [H, H]
    // d_in[3] = bias[H]: softmax-shift-invariant, intentionally unused.
    float* out = (float*)d_out;                    // [B, L]

    float* v_t      = (float*)d_ws;                // BB*HH floats (153600 B, 16B-aligned)
    float* energies = v_t + BB * HH;               // LL*BB floats = 1 MB, [L][B]

    compute_v<<<(BB * HH + 255) / 256, 256, 0, stream>>>(W, hidden, v_t);
    compute_energies<<<(LL * BB) / 4, 256, 0, stream>>>(
        (const float4*)qv, (const float4*)v_t, energies);
    softmax_rows<<<BB, 256, 0, stream>>>(energies, out);
}